// Round 19
// baseline (194.431 us; speedup 1.0000x reference)
//
#include <hip/hip_runtime.h>
#include <hip/hip_bf16.h>

#define D 64
#define MARGIN 8e-5f   // widened: covers np-noise (1.6e-5) + 9-bit packing (1.5e-5)
#define KS 2           // k-split factor (KS=2+LDS staging is the proven optimum)

typedef __attribute__((ext_vector_type(8))) short bf16x8;
typedef __attribute__((ext_vector_type(4))) float f32x4;
typedef __attribute__((ext_vector_type(4))) unsigned uint4v;

// ---------------------------------------------------------------------------
// VectorQuantizer — R16 structure + packed-index top-2 screen.
// Harness ref = numpy-f32 recompute; argmin must bit-match np-f32 (xx
// pairwise-8 sum, sequential-d FMA sgemm, first-min). Screen: split-bf16
// MFMA proxy acc = dot - ee/2 (6-MFMA chain seeded C = -ee/2), argmax(acc)
// == argmin(dist); codes tile-major pre-permuted, LDS-staged double-buffered
// (T14) -> 1 VMEM/wave/tile; KS=2 (R18 lesson: KS=4 doubles HBM x-stream,
// occupancy doesn't rise). Top-2 tracked on PACKED floats: low 9 mantissa
// bits replaced by complemented slice-local code index (v_and_or_b32) ->
// update = med3 + max (3 ops/value, no cmp/cndmask/index regs); packing
// error <=512ulp lands inside MARGIN band -> np-exact resolve. Emits
// per-slice (m1,m2 packed, bi) SoA planes + xxp. vq_epilogue (2048 x 64
// rows): slice merge (ascending + strict > == np first-min), margin, inline
// block-coop np-f32-exact resolve (256thr x 4 codes, eT-coalesced, LDS-
// broadcast x row [R14 spill lesson]), ZERO fp atomics (R13: f64 atomicAdd
// = CAS loop) — plain lossA[block] store, ballot+rank compaction.
// vq_histperp: 16-block LDS hist (R17 lesson: direct per-row counts atomics
// on 32 lines serialize ~200us) + last-block finalize. Prep zeroes counters.
// d_out (float): quantized[N*D] | loss[1] | indices[N] | perplexity[1]
// ws: counts u32[K] | done u32 | pad | neh f32[K] | eenp f32[K]
//     | ehs bf16-tiles[K*256B] | eT f32[D*K]
//     | m1p f32[KS*N] | m2p f32[KS*N] | bip i32[KS*N] | xxp f32[N]
//     | lossA f64[N/64]
// ---------------------------------------------------------------------------

__device__ __forceinline__ float np_pairwise_sumsq64(const float* a) {
    float r[8];
#pragma unroll
    for (int j = 0; j < 8; ++j) r[j] = __fmul_rn(a[j], a[j]);
#pragma unroll
    for (int i = 8; i < 64; i += 8)
#pragma unroll
        for (int j = 0; j < 8; ++j)
            r[j] = __fadd_rn(r[j], __fmul_rn(a[i + j], a[i + j]));
    return __fadd_rn(
        __fadd_rn(__fadd_rn(r[0], r[1]), __fadd_rn(r[2], r[3])),
        __fadd_rn(__fadd_rn(r[4], r[5]), __fadd_rn(r[6], r[7])));
}

#define CVT8(F0, F1, H, L)                                                    \
    do {                                                                      \
        float _f[8] = {F0.x, F0.y, F0.z, F0.w, F1.x, F1.y, F1.z, F1.w};       \
        _Pragma("unroll") for (int _i = 0; _i < 8; ++_i) {                    \
            unsigned _u = __float_as_uint(_f[_i]);                            \
            unsigned _hb = (_u + 0x7fffu + ((_u >> 16) & 1u)) >> 16;          \
            float _hf = __uint_as_float(_hb << 16);                           \
            float _r = _f[_i] - _hf;                                          \
            unsigned _u2 = __float_as_uint(_r);                               \
            unsigned _lb = (_u2 + 0x7fffu + ((_u2 >> 16) & 1u)) >> 16;        \
            H[_i] = (short)_hb;                                               \
            L[_i] = (short)_lb;                                               \
        }                                                                     \
    } while (0)

// prep: [0,64) ehs tile-major; [64,68) sumsq; [68,324) eT; 324 zero counters
__global__ __launch_bounds__(256) void vq_prep_all(
    const float* __restrict__ emb, int K,
    float* __restrict__ eenp, float* __restrict__ neh,
    unsigned short* __restrict__ ehs, float* __restrict__ eT,
    unsigned* __restrict__ counts, unsigned* __restrict__ done) {
    int b = blockIdx.x;
    if (b < 64) {
        int t = b * 256 + threadIdx.x;     // (tile, sec, lane): 16384 frags
        int tile = t >> 8, r = t & 255, s = r >> 6, l = r & 63;
        int sub = l & 15, grp = l >> 4;
        int k = tile * 16 + sub;
        int d0 = ((s & 1) << 5) + (grp << 3);
        const float* e = emb + (size_t)k * D + d0;
        float4 f0 = *(const float4*)e;
        float4 f1 = *(const float4*)(e + 4);
        bf16x8 h, lo;
        CVT8(f0, f1, h, lo);
        *(bf16x8*)(ehs + (size_t)t * 8) = (s >> 1) ? lo : h;  // s0,s1=eh s2,s3=el
    } else if (b < 68) {
        int k = (b - 64) * 256 + threadIdx.x;   // 1024 codes
        float s = np_pairwise_sumsq64(emb + (size_t)k * D);
        eenp[k] = s;
        neh[k] = -0.5f * s;
    } else if (b < 324) {
        int t = (b - 68) * 256 + threadIdx.x;   // 65536 = D*K, coalesced write
        int d = t / K, k = t - d * K;
        eT[t] = emb[(size_t)k * D + d];
    } else {
#pragma unroll
        for (int i = 0; i < 4; ++i) {
            int c = threadIdx.x + 256 * i;
            if (c < K) counts[c] = 0u;
        }
        if (threadIdx.x == 0) *done = 0u;
    }
}

__global__ __launch_bounds__(256) void vq_screen(
    const float* __restrict__ x, const unsigned short* __restrict__ ehs,
    const float* __restrict__ neh, int N, int K,
    float* __restrict__ m1p, float* __restrict__ m2p, int* __restrict__ bip,
    float* __restrict__ xxp) {
    const int tid = threadIdx.x;
    const int lane = tid & 63;
    const int wid = tid >> 6;
    const int kslice = blockIdx.x & (KS - 1);
    const int rowblk = blockIdx.x >> 1;  // KS == 2
    const int row0 = rowblk * 256 + wid * 64;  // 64 rows/wave
    const int sub = lane & 15, grp = lane >> 4;
    const int g4 = grp << 2;
    const int k0 = kslice * (K / KS);
    const int NT = (K / KS) >> 4;        // 16-code tiles in this slice (32)
    const int t0 = k0 >> 4;

    __shared__ __align__(16) unsigned short lds[2][2048];  // 2 bufs x 4KB

    // persistent B frags: x rows, split bf16, 4 row-tiles x 2 k-slices.
    // Also accumulate per-lane sumsq (loss-only, f32) and grp-reduce -> xx.
    bf16x8 xh[4][2], xl[4][2];
    float xq[4];
#pragma unroll
    for (int rt = 0; rt < 4; ++rt) {
        xq[rt] = 0.f;
        const float* xrow = x + (((size_t)(row0 + (rt << 4) + sub)) << 6) + (grp << 3);
#pragma unroll
        for (int s = 0; s < 2; ++s) {
            float4 f0 = *(const float4*)(xrow + (s << 5));
            float4 f1 = *(const float4*)(xrow + (s << 5) + 4);
            xq[rt] = fmaf(f0.x, f0.x, xq[rt]); xq[rt] = fmaf(f0.y, f0.y, xq[rt]);
            xq[rt] = fmaf(f0.z, f0.z, xq[rt]); xq[rt] = fmaf(f0.w, f0.w, xq[rt]);
            xq[rt] = fmaf(f1.x, f1.x, xq[rt]); xq[rt] = fmaf(f1.y, f1.y, xq[rt]);
            xq[rt] = fmaf(f1.z, f1.z, xq[rt]); xq[rt] = fmaf(f1.w, f1.w, xq[rt]);
            CVT8(f0, f1, xh[rt][s], xl[rt][s]);
        }
    }
#pragma unroll
    for (int rt = 0; rt < 4; ++rt) {
        xq[rt] += __shfl_xor(xq[rt], 16);
        xq[rt] += __shfl_xor(xq[rt], 32);  // all grps summed; lane<16 = row xx
    }

    // packed top-2: low 9 mantissa bits = complemented slice-local code idx
    float m1[4], m2[4];
#pragma unroll
    for (int rt = 0; rt < 4; ++rt) { m1[rt] = -3e38f; m2[rt] = -3e38f; }

    // staging: this thread's 16B slot (wave wid stages section wid)
    const unsigned short* sbase = ehs + ((size_t)t0 << 11);  // tile stride 2048 ush
    const int slot = (wid << 9) + (lane << 3);               // ushort offset

    uint4v tmp = *(const uint4v*)(sbase + slot);             // tile 0
    *(uint4v*)&lds[0][slot] = tmp;
    __syncthreads();

    for (int t = 0; t < NT; ++t) {
        const int cur = t & 1;
        if (t + 1 < NT)  // T14: issue next-tile load before compute
            tmp = *(const uint4v*)(sbase + ((size_t)(t + 1) << 11) + slot);

        f32x4 cb = *(const f32x4*)(neh + k0 + (t << 4) + g4);
        const bf16x8* L = (const bf16x8*)&lds[cur][0];
        bf16x8 a0 = L[lane];        // eh d[0,32)
        bf16x8 a1 = L[64 + lane];   // eh d[32,64)
        bf16x8 a2 = L[128 + lane];  // el d[0,32)
        bf16x8 a3 = L[192 + lane];  // el d[32,64)

        f32x4 acc[4];
#pragma unroll
        for (int rt = 0; rt < 4; ++rt)
            acc[rt] = __builtin_amdgcn_mfma_f32_16x16x32_bf16(a0, xh[rt][0], cb, 0, 0, 0);
#pragma unroll
        for (int rt = 0; rt < 4; ++rt)
            acc[rt] = __builtin_amdgcn_mfma_f32_16x16x32_bf16(a2, xh[rt][0], acc[rt], 0, 0, 0);
#pragma unroll
        for (int rt = 0; rt < 4; ++rt)
            acc[rt] = __builtin_amdgcn_mfma_f32_16x16x32_bf16(a0, xl[rt][0], acc[rt], 0, 0, 0);
#pragma unroll
        for (int rt = 0; rt < 4; ++rt)
            acc[rt] = __builtin_amdgcn_mfma_f32_16x16x32_bf16(a1, xh[rt][1], acc[rt], 0, 0, 0);
#pragma unroll
        for (int rt = 0; rt < 4; ++rt)
            acc[rt] = __builtin_amdgcn_mfma_f32_16x16x32_bf16(a3, xh[rt][1], acc[rt], 0, 0, 0);
#pragma unroll
        for (int rt = 0; rt < 4; ++rt)
            acc[rt] = __builtin_amdgcn_mfma_f32_16x16x32_bf16(a1, xl[rt][1], acc[rt], 0, 0, 0);

        // packed top-2 update: 3 VALU/value (and_or + med3 + max)
        const int baset = 511 - (t << 4) - g4;  // complemented local idx, j=0
#pragma unroll
        for (int rt = 0; rt < 4; ++rt) {
#pragma unroll
            for (int j = 0; j < 4; ++j) {
                unsigned pv = (__float_as_uint(acc[rt][j]) & 0xFFFFFE00u)
                              | (unsigned)(baset - j);
                float p = __uint_as_float(pv);
                m2[rt] = fminf(fmaxf(p, m2[rt]), m1[rt]);  // med3(p,m2,m1)
                m1[rt] = fmaxf(p, m1[rt]);
            }
        }

        if (t + 1 < NT)  // T14: write-late into the other buffer
            *(uint4v*)&lds[cur ^ 1][slot] = tmp;
        __syncthreads();
    }

    // merge the 4 code-groups: pure min/max on packed values
#pragma unroll
    for (int rt = 0; rt < 4; ++rt) {
#pragma unroll
        for (int off = 16; off <= 32; off <<= 1) {
            float om1 = __shfl_xor(m1[rt], off);
            float om2 = __shfl_xor(m2[rt], off);
            float lo = fminf(m1[rt], om1);
            m1[rt] = fmaxf(m1[rt], om1);
            m2[rt] = fmaxf(lo, fmaxf(m2[rt], om2));
        }
    }

    // emit coalesced SoA planes (lanes 0-15 own 16 consecutive rows per rt)
    if (lane < 16) {
#pragma unroll
        for (int rt = 0; rt < 4; ++rt) {
            size_t idx = (size_t)kslice * N + row0 + (rt << 4) + lane;
            int local = 511 - (int)(__float_as_uint(m1[rt]) & 511u);
            m1p[idx] = m1[rt];
            m2p[idx] = m2[rt];
            bip[idx] = k0 + local;
            if (kslice == 0) xxp[row0 + (rt << 4) + lane] = xq[rt];
        }
    }
}

// decide + inline block-cooperative np-exact resolve + idx + loss (plain
// store, zero atomics) + coalesced quantized write. 64 rows/block.
__global__ __launch_bounds__(256) void vq_epilogue(
    const float* __restrict__ x, const float* __restrict__ emb,
    const float* __restrict__ eT, const float* __restrict__ eenp,
    const float* __restrict__ m1p, const float* __restrict__ m2p,
    const int* __restrict__ bip, const float* __restrict__ xxp, int N, int K,
    float* __restrict__ outq, float* __restrict__ outidx,
    double* __restrict__ lossA) {
    const int tid = threadIdx.x;
    const int rows0 = blockIdx.x * 64;
    __shared__ int sdec[64];
    __shared__ int samb[64];
    __shared__ int snamb;
    __shared__ float sxrow[64];
    __shared__ float swm[4];
    __shared__ int swi[4];

    double lacc = 0.0;  // only tid 0's copy is ultimately stored

    if (tid < 64) {  // phase A: wave 0 decides
        int r = rows0 + tid;
        float gm1 = m1p[r], gm2 = m2p[r];
        int gbi = bip[r];
#pragma unroll
        for (int s = 1; s < KS; ++s) {
            size_t idx = (size_t)s * N + r;
            float m1b = m1p[idx], m2b = m2p[idx];
            int bb = bip[idx];
            // higher slice = higher codes: strictly greater only (first-min)
            bool take = m1b > gm1;
            float lo = fminf(gm1, m1b);
            gm1 = fmaxf(gm1, m1b);
            gm2 = fmaxf(lo, fmaxf(gm2, m2b));
            gbi = take ? bb : gbi;
        }
        bool amb = 2.0f * (gm1 - gm2) < MARGIN;
        unsigned long long mask = __ballot(amb);   // wave 0 only
        int dec = gbi;
        double lpart = 0.0;
        if (amb) {
            int rank = __popcll(mask & ((1ull << tid) - 1ull));
            samb[rank] = tid;   // compacted ambiguous local rows, no atomic
            dec = -1;
        } else {
            outidx[r] = (float)dec;
            // strip 9 packed index bits, then ||x-e||^2 = xx - 2*m1
            float gm1v = __uint_as_float(__float_as_uint(gm1) & 0xFFFFFE00u);
            lpart = (double)(xxp[r] - 2.0f * gm1v);
        }
        sdec[tid] = dec;
        if (tid == 0) snamb = __popcll(mask);
#pragma unroll
        for (int off = 32; off; off >>= 1) lpart += __shfl_down(lpart, off);
        if (tid == 0) lacc = lpart;
    }
    __syncthreads();

    // inline resolve: whole block per ambiguous row; 256 thr x 4 codes each.
    // np-f32-exact: xx pairwise-8 (LDS broadcast), sequential-d FMA chains,
    // ascending thread/wave order + strict < + idx tie-break = np first-min.
    const int namb = snamb;
    const int w = tid >> 6, l = tid & 63;
    const f32x4* eT4 = (const f32x4*)eT;  // [D][K/4]
    for (int j = 0; j < namb; ++j) {
        int lr = samb[j];
        int row = rows0 + lr;
        if (tid < 64) sxrow[tid] = x[(size_t)row * D + tid];
        __syncthreads();
        float xx = np_pairwise_sumsq64(sxrow);
        f32x4 dt = (f32x4){0.f, 0.f, 0.f, 0.f};
#pragma unroll 8
        for (int d = 0; d < D; ++d) {
            f32x4 ev = eT4[(size_t)d * 256 + tid];
            float xv = sxrow[d];
            dt[0] = __fmaf_rn(xv, ev[0], dt[0]);
            dt[1] = __fmaf_rn(xv, ev[1], dt[1]);
            dt[2] = __fmaf_rn(xv, ev[2], dt[2]);
            dt[3] = __fmaf_rn(xv, ev[3], dt[3]);
        }
        float bm = 1e30f;
        int bi = 0;
#pragma unroll
        for (int jj = 0; jj < 4; ++jj) {
            int k = (tid << 2) + jj;  // ascending within thread
            float dist = __fsub_rn(__fadd_rn(xx, eenp[k]),
                                   __fmul_rn(2.0f, dt[jj]));
            if (dist < bm) { bm = dist; bi = k; }
        }
#pragma unroll
        for (int off = 1; off < 64; off <<= 1) {
            float ov = __shfl_xor(bm, off);
            int oi = __shfl_xor(bi, off);
            if (ov < bm || (ov == bm && oi < bi)) { bm = ov; bi = oi; }
        }
        if (l == 0) { swm[w] = bm; swi[w] = bi; }
        __syncthreads();
        if (tid == 0) {  // cross-wave merge, ascending wave order
            float fm = swm[0];
            int fi = swi[0];
#pragma unroll
            for (int ww = 1; ww < 4; ++ww) {
                float ov = swm[ww];
                int oi = swi[ww];
                if (ov < fm || (ov == fm && oi < fi)) { fm = ov; fi = oi; }
            }
            sdec[lr] = fi;
            outidx[row] = (float)fi;
            lacc += (double)fm;  // fm = ||x-e||^2 (np-f32), no atomic
        }
        __syncthreads();
    }
    if (tid == 0) lossA[blockIdx.x] = lacc;  // single plain store per block

    // phase B: quantized gather-write; each wave stores 1KB contiguous/pass
    const int chunk = tid & 15, rl = tid >> 4;  // 16 rows x 16 chunks
#pragma unroll
    for (int p = 0; p < 4; ++p) {
        int lr = p * 16 + rl;
        int dp = sdec[lr];
        float4 ev = *(const float4*)(emb + (size_t)dp * D + chunk * 4);
        *(float4*)(outq + (size_t)(rows0 + lr) * D + chunk * 4) = ev;
    }
}

// histogram of outidx via LDS (16 fat blocks) + last-block finalize
__global__ __launch_bounds__(256) void vq_histperp(
    const float* __restrict__ outidx, int N, int K,
    unsigned* __restrict__ counts, unsigned* __restrict__ done,
    const double* __restrict__ lossA, int nA,
    float* __restrict__ out_loss, float* __restrict__ out_perp) {
    __shared__ unsigned h[1024];
    __shared__ unsigned rank_s;
#pragma unroll
    for (int i = 0; i < 4; ++i) h[threadIdx.x + 256 * i] = 0;
    __syncthreads();
    int per = N / gridDim.x;
    int base = blockIdx.x * per;
    for (int i = threadIdx.x; i < per; i += 256) {
        int k = (int)outidx[base + i];
        atomicAdd(&h[k], 1u);
    }
    __syncthreads();
#pragma unroll
    for (int i = 0; i < 4; ++i) {
        int b = threadIdx.x + 256 * i;
        unsigned v = h[b];
        if (b < K && v) atomicAdd(counts + b, v);
    }
    __threadfence();
    if (threadIdx.x == 0) rank_s = atomicAdd(done, 1u);
    __syncthreads();
    if (rank_s == gridDim.x - 1) {  // last block: counts complete
        double part = 0.0;
        for (int k = threadIdx.x; k < K; k += 256) {
            // device-scope atomic read (cross-XCD-safe)
            unsigned c = atomicAdd(counts + k, 0u);
            double p = (double)c / (double)N;
            part += p * log(p + 1e-10);
        }
        double lsum = 0.0;
        for (int i = threadIdx.x; i < nA; i += 256) lsum += lossA[i];
#pragma unroll
        for (int off = 32; off; off >>= 1) {
            part += __shfl_down(part, off);
            lsum += __shfl_down(lsum, off);
        }
        __shared__ double ls[4], ls2[4];
        if ((threadIdx.x & 63) == 0) {
            ls[threadIdx.x >> 6] = part;
            ls2[threadIdx.x >> 6] = lsum;
        }
        __syncthreads();
        if (threadIdx.x == 0) {
            double s = ls[0] + ls[1] + ls[2] + ls[3];
            double L = ls2[0] + ls2[1] + ls2[2] + ls2[3];
            *out_perp = (float)exp(-s);
            *out_loss = (float)(1.25 * (L / ((double)N * (double)D)));
        }
    }
}

extern "C" void kernel_launch(void* const* d_in, const int* in_sizes, int n_in,
                              void* d_out, int out_size, void* d_ws, size_t ws_size,
                              hipStream_t stream) {
    const float* x = (const float*)d_in[0];
    const float* emb = (const float*)d_in[1];
    int N = in_sizes[0] / D;
    int K = in_sizes[1] / D;

    float* outq = (float*)d_out;
    float* out_loss = outq + (size_t)N * D;
    float* outidx = out_loss + 1;
    float* out_perp = outidx + N;

    char* ws = (char*)d_ws;
    unsigned* counts = (unsigned*)ws;                          // K*4
    unsigned* done = (unsigned*)(ws + (size_t)K * 4);          // 4 (+12 pad)
    size_t off = (size_t)K * 4 + 16;
    float* neh = (float*)(ws + off);            off += (size_t)K * 4;
    float* eenp = (float*)(ws + off);           off += (size_t)K * 4;
    unsigned short* ehs = (unsigned short*)(ws + off);  off += (size_t)K * 256;
    float* eT = (float*)(ws + off);              off += (size_t)K * D * 4;
    float* m1p = (float*)(ws + off);             off += (size_t)KS * N * 4;
    float* m2p = (float*)(ws + off);             off += (size_t)KS * N * 4;
    int* bip = (int*)(ws + off);                 off += (size_t)KS * N * 4;
    float* xxp = (float*)(ws + off);             off += (size_t)N * 4;
    int nA = N / 64;
    double* lossA = (double*)(ws + off);         off += (size_t)nA * 8;

    // prep: 64 ehs + 4 sums + 256 eT + 1 zero-counters = 325 blocks
    vq_prep_all<<<325, 256, 0, stream>>>(emb, K, eenp, neh, ehs, eT,
                                         counts, done);
    vq_screen<<<(N / 256) * KS, 256, 0, stream>>>(x, ehs, neh, N, K,
                                                  m1p, m2p, bip, xxp);
    vq_epilogue<<<N / 64, 256, 0, stream>>>(x, emb, eT, eenp, m1p, m2p, bip,
                                            xxp, N, K, outq, outidx, lossA);
    vq_histperp<<<16, 256, 0, stream>>>(outidx, N, K, counts, done,
                                        lossA, nA, out_loss, out_perp);
}

// Round 20
// 166.354 us; speedup vs baseline: 1.1688x; 1.1688x over previous
//
#include <hip/hip_runtime.h>
#include <hip/hip_bf16.h>

#define D 64
#define MARGIN 8e-5f   // covers np-noise (1.6e-5) + 9-bit packing (1.5e-5)
#define KS 2           // k-split factor (KS=2+LDS staging is the proven optimum)
#define RB 8           // resolve batch: rows per block-pass (shares eT stream)

typedef __attribute__((ext_vector_type(8))) short bf16x8;
typedef __attribute__((ext_vector_type(4))) float f32x4;
typedef __attribute__((ext_vector_type(4))) unsigned uint4v;

// ---------------------------------------------------------------------------
// VectorQuantizer. Harness ref = numpy-f32 recompute; argmin must bit-match
// np-f32 (xx pairwise-8 sum, sequential-d FMA sgemm, first-min). Screen:
// split-bf16 MFMA proxy acc = dot - ee/2 (6-MFMA chain seeded C = -ee/2),
// argmax(acc) == argmin(dist); codes tile-major, LDS-staged double-buffered
// -> 1 VMEM/wave/tile; packed top-2 (low 9 mantissa bits = complemented
// slice-local idx; med3+max update). vq_epilogue: decide only (ascending
// slice + strict > == np first-min, margin), idx + loss for decided rows,
// ambiguous -> list (ballot+rank, 1 u32 atomic/block), coalesced quantized
// write (skip ambiguous). vq_resolve: BATCHED np-f32-exact resolve — 8 rows
// per block-pass share ONE eT stream (R19 lesson: per-row eT streaming is
// ~22us/1000 rows; batching cuts total eT traffic 1GB -> 130MB). ZERO fp
// atomics anywhere (R13: f64 atomicAdd = CAS loop). vq_histperp: 16-block
// LDS hist (R17 lesson) + last-block reduce(lossA,lossR) + finalize.
// d_out (float): quantized[N*D] | loss[1] | indices[N] | perplexity[1]
// ws: counts u32[K] | done u32 | nunc u32 | pad | neh f32[K] | eenp f32[K]
//     | ehs bf16-tiles[K*256B] | eT f32[D*K]
//     | m1p f32[KS*N] | m2p f32[KS*N] | bip i32[KS*N] | xxp f32[N]
//     | list u32[N] | lossA f64[N/64] | lossR f64[128]
// ---------------------------------------------------------------------------

__device__ __forceinline__ float np_pairwise_sumsq64(const float* a) {
    float r[8];
#pragma unroll
    for (int j = 0; j < 8; ++j) r[j] = __fmul_rn(a[j], a[j]);
#pragma unroll
    for (int i = 8; i < 64; i += 8)
#pragma unroll
        for (int j = 0; j < 8; ++j)
            r[j] = __fadd_rn(r[j], __fmul_rn(a[i + j], a[i + j]));
    return __fadd_rn(
        __fadd_rn(__fadd_rn(r[0], r[1]), __fadd_rn(r[2], r[3])),
        __fadd_rn(__fadd_rn(r[4], r[5]), __fadd_rn(r[6], r[7])));
}

#define CVT8(F0, F1, H, L)                                                    \
    do {                                                                      \
        float _f[8] = {F0.x, F0.y, F0.z, F0.w, F1.x, F1.y, F1.z, F1.w};       \
        _Pragma("unroll") for (int _i = 0; _i < 8; ++_i) {                    \
            unsigned _u = __float_as_uint(_f[_i]);                            \
            unsigned _hb = (_u + 0x7fffu + ((_u >> 16) & 1u)) >> 16;          \
            float _hf = __uint_as_float(_hb << 16);                           \
            float _r = _f[_i] - _hf;                                          \
            unsigned _u2 = __float_as_uint(_r);                               \
            unsigned _lb = (_u2 + 0x7fffu + ((_u2 >> 16) & 1u)) >> 16;        \
            H[_i] = (short)_hb;                                               \
            L[_i] = (short)_lb;                                               \
        }                                                                     \
    } while (0)

// prep: [0,64) ehs tile-major; [64,68) sumsq; [68,324) eT; 324 zero counters
__global__ __launch_bounds__(256) void vq_prep_all(
    const float* __restrict__ emb, int K,
    float* __restrict__ eenp, float* __restrict__ neh,
    unsigned short* __restrict__ ehs, float* __restrict__ eT,
    unsigned* __restrict__ counts, unsigned* __restrict__ done,
    unsigned* __restrict__ nunc) {
    int b = blockIdx.x;
    if (b < 64) {
        int t = b * 256 + threadIdx.x;     // (tile, sec, lane): 16384 frags
        int tile = t >> 8, r = t & 255, s = r >> 6, l = r & 63;
        int sub = l & 15, grp = l >> 4;
        int k = tile * 16 + sub;
        int d0 = ((s & 1) << 5) + (grp << 3);
        const float* e = emb + (size_t)k * D + d0;
        float4 f0 = *(const float4*)e;
        float4 f1 = *(const float4*)(e + 4);
        bf16x8 h, lo;
        CVT8(f0, f1, h, lo);
        *(bf16x8*)(ehs + (size_t)t * 8) = (s >> 1) ? lo : h;  // s0,s1=eh s2,s3=el
    } else if (b < 68) {
        int k = (b - 64) * 256 + threadIdx.x;   // 1024 codes
        float s = np_pairwise_sumsq64(emb + (size_t)k * D);
        eenp[k] = s;
        neh[k] = -0.5f * s;
    } else if (b < 324) {
        int t = (b - 68) * 256 + threadIdx.x;   // 65536 = D*K, coalesced write
        int d = t / K, k = t - d * K;
        eT[t] = emb[(size_t)k * D + d];
    } else {
#pragma unroll
        for (int i = 0; i < 4; ++i) {
            int c = threadIdx.x + 256 * i;
            if (c < K) counts[c] = 0u;
        }
        if (threadIdx.x == 0) { *done = 0u; *nunc = 0u; }
    }
}

__global__ __launch_bounds__(256) void vq_screen(
    const float* __restrict__ x, const unsigned short* __restrict__ ehs,
    const float* __restrict__ neh, int N, int K,
    float* __restrict__ m1p, float* __restrict__ m2p, int* __restrict__ bip,
    float* __restrict__ xxp) {
    const int tid = threadIdx.x;
    const int lane = tid & 63;
    const int wid = tid >> 6;
    const int kslice = blockIdx.x & (KS - 1);
    const int rowblk = blockIdx.x >> 1;  // KS == 2
    const int row0 = rowblk * 256 + wid * 64;  // 64 rows/wave
    const int sub = lane & 15, grp = lane >> 4;
    const int g4 = grp << 2;
    const int k0 = kslice * (K / KS);
    const int NT = (K / KS) >> 4;        // 16-code tiles in this slice (32)
    const int t0 = k0 >> 4;

    __shared__ __align__(16) unsigned short lds[2][2048];  // 2 bufs x 4KB

    // persistent B frags: x rows, split bf16, 4 row-tiles x 2 k-slices.
    // Also accumulate per-lane sumsq (loss-only, f32) and grp-reduce -> xx.
    bf16x8 xh[4][2], xl[4][2];
    float xq[4];
#pragma unroll
    for (int rt = 0; rt < 4; ++rt) {
        xq[rt] = 0.f;
        const float* xrow = x + (((size_t)(row0 + (rt << 4) + sub)) << 6) + (grp << 3);
#pragma unroll
        for (int s = 0; s < 2; ++s) {
            float4 f0 = *(const float4*)(xrow + (s << 5));
            float4 f1 = *(const float4*)(xrow + (s << 5) + 4);
            xq[rt] = fmaf(f0.x, f0.x, xq[rt]); xq[rt] = fmaf(f0.y, f0.y, xq[rt]);
            xq[rt] = fmaf(f0.z, f0.z, xq[rt]); xq[rt] = fmaf(f0.w, f0.w, xq[rt]);
            xq[rt] = fmaf(f1.x, f1.x, xq[rt]); xq[rt] = fmaf(f1.y, f1.y, xq[rt]);
            xq[rt] = fmaf(f1.z, f1.z, xq[rt]); xq[rt] = fmaf(f1.w, f1.w, xq[rt]);
            CVT8(f0, f1, xh[rt][s], xl[rt][s]);
        }
    }
#pragma unroll
    for (int rt = 0; rt < 4; ++rt) {
        xq[rt] += __shfl_xor(xq[rt], 16);
        xq[rt] += __shfl_xor(xq[rt], 32);  // all grps summed; lane<16 = row xx
    }

    // packed top-2: low 9 mantissa bits = complemented slice-local code idx
    float m1[4], m2[4];
#pragma unroll
    for (int rt = 0; rt < 4; ++rt) { m1[rt] = -3e38f; m2[rt] = -3e38f; }

    // staging: this thread's 16B slot (wave wid stages section wid)
    const unsigned short* sbase = ehs + ((size_t)t0 << 11);  // tile stride 2048 ush
    const int slot = (wid << 9) + (lane << 3);               // ushort offset

    uint4v tmp = *(const uint4v*)(sbase + slot);             // tile 0
    *(uint4v*)&lds[0][slot] = tmp;
    __syncthreads();

    for (int t = 0; t < NT; ++t) {
        const int cur = t & 1;
        if (t + 1 < NT)  // T14: issue next-tile load before compute
            tmp = *(const uint4v*)(sbase + ((size_t)(t + 1) << 11) + slot);

        f32x4 cb = *(const f32x4*)(neh + k0 + (t << 4) + g4);
        const bf16x8* L = (const bf16x8*)&lds[cur][0];
        bf16x8 a0 = L[lane];        // eh d[0,32)
        bf16x8 a1 = L[64 + lane];   // eh d[32,64)
        bf16x8 a2 = L[128 + lane];  // el d[0,32)
        bf16x8 a3 = L[192 + lane];  // el d[32,64)

        f32x4 acc[4];
#pragma unroll
        for (int rt = 0; rt < 4; ++rt)
            acc[rt] = __builtin_amdgcn_mfma_f32_16x16x32_bf16(a0, xh[rt][0], cb, 0, 0, 0);
#pragma unroll
        for (int rt = 0; rt < 4; ++rt)
            acc[rt] = __builtin_amdgcn_mfma_f32_16x16x32_bf16(a2, xh[rt][0], acc[rt], 0, 0, 0);
#pragma unroll
        for (int rt = 0; rt < 4; ++rt)
            acc[rt] = __builtin_amdgcn_mfma_f32_16x16x32_bf16(a0, xl[rt][0], acc[rt], 0, 0, 0);
#pragma unroll
        for (int rt = 0; rt < 4; ++rt)
            acc[rt] = __builtin_amdgcn_mfma_f32_16x16x32_bf16(a1, xh[rt][1], acc[rt], 0, 0, 0);
#pragma unroll
        for (int rt = 0; rt < 4; ++rt)
            acc[rt] = __builtin_amdgcn_mfma_f32_16x16x32_bf16(a3, xh[rt][1], acc[rt], 0, 0, 0);
#pragma unroll
        for (int rt = 0; rt < 4; ++rt)
            acc[rt] = __builtin_amdgcn_mfma_f32_16x16x32_bf16(a1, xl[rt][1], acc[rt], 0, 0, 0);

        // packed top-2 update: 3 VALU/value (and_or + med3 + max)
        const int baset = 511 - (t << 4) - g4;  // complemented local idx, j=0
#pragma unroll
        for (int rt = 0; rt < 4; ++rt) {
#pragma unroll
            for (int j = 0; j < 4; ++j) {
                unsigned pv = (__float_as_uint(acc[rt][j]) & 0xFFFFFE00u)
                              | (unsigned)(baset - j);
                float p = __uint_as_float(pv);
                m2[rt] = fminf(fmaxf(p, m2[rt]), m1[rt]);  // med3(p,m2,m1)
                m1[rt] = fmaxf(p, m1[rt]);
            }
        }

        if (t + 1 < NT)  // T14: write-late into the other buffer
            *(uint4v*)&lds[cur ^ 1][slot] = tmp;
        __syncthreads();
    }

    // merge the 4 code-groups: pure min/max on packed values
#pragma unroll
    for (int rt = 0; rt < 4; ++rt) {
#pragma unroll
        for (int off = 16; off <= 32; off <<= 1) {
            float om1 = __shfl_xor(m1[rt], off);
            float om2 = __shfl_xor(m2[rt], off);
            float lo = fminf(m1[rt], om1);
            m1[rt] = fmaxf(m1[rt], om1);
            m2[rt] = fmaxf(lo, fmaxf(m2[rt], om2));
        }
    }

    // emit coalesced SoA planes (lanes 0-15 own 16 consecutive rows per rt)
    if (lane < 16) {
#pragma unroll
        for (int rt = 0; rt < 4; ++rt) {
            size_t idx = (size_t)kslice * N + row0 + (rt << 4) + lane;
            int local = 511 - (int)(__float_as_uint(m1[rt]) & 511u);
            m1p[idx] = m1[rt];
            m2p[idx] = m2[rt];
            bip[idx] = k0 + local;
            if (kslice == 0) xxp[row0 + (rt << 4) + lane] = xq[rt];
        }
    }
}

// decide + idx + loss (plain store) + list ambiguous + quantized write
__global__ __launch_bounds__(256) void vq_epilogue(
    const float* __restrict__ emb,
    const float* __restrict__ m1p, const float* __restrict__ m2p,
    const int* __restrict__ bip, const float* __restrict__ xxp, int N,
    float* __restrict__ outq, float* __restrict__ outidx,
    double* __restrict__ lossA,
    unsigned* __restrict__ nunc, unsigned* __restrict__ list) {
    const int tid = threadIdx.x;
    const int rows0 = blockIdx.x * 64;
    __shared__ int sdec[64];

    if (tid < 64) {  // phase A: wave 0 decides
        int r = rows0 + tid;
        float gm1 = m1p[r], gm2 = m2p[r];
        int gbi = bip[r];
#pragma unroll
        for (int s = 1; s < KS; ++s) {
            size_t idx = (size_t)s * N + r;
            float m1b = m1p[idx], m2b = m2p[idx];
            int bb = bip[idx];
            // higher slice = higher codes: strictly greater only (first-min)
            bool take = m1b > gm1;
            float lo = fminf(gm1, m1b);
            gm1 = fmaxf(gm1, m1b);
            gm2 = fmaxf(lo, fmaxf(gm2, m2b));
            gbi = take ? bb : gbi;
        }
        bool amb = 2.0f * (gm1 - gm2) < MARGIN;
        unsigned long long mask = __ballot(amb);   // wave 0 only
        int cnt = __popcll(mask);
        unsigned base = 0;
        if (tid == 0 && cnt) base = atomicAdd(nunc, (unsigned)cnt);
        base = __shfl(base, 0);
        int dec = gbi;
        double lpart = 0.0;
        if (amb) {
            int rank = __popcll(mask & ((1ull << tid) - 1ull));
            list[base + rank] = (unsigned)r;
            dec = -1;
        } else {
            outidx[r] = (float)dec;
            // strip 9 packed index bits, then ||x-e||^2 = xx - 2*m1
            float gm1v = __uint_as_float(__float_as_uint(gm1) & 0xFFFFFE00u);
            lpart = (double)(xxp[r] - 2.0f * gm1v);
        }
        sdec[tid] = dec;
#pragma unroll
        for (int off = 32; off; off >>= 1) lpart += __shfl_down(lpart, off);
        if (tid == 0) lossA[blockIdx.x] = lpart;  // plain store, no atomic
    }
    __syncthreads();

    // phase B: quantized gather-write (skip ambiguous; resolver writes them)
    const int chunk = tid & 15, rl = tid >> 4;  // 16 rows x 16 chunks
#pragma unroll
    for (int p = 0; p < 4; ++p) {
        int lr = p * 16 + rl;
        int dp = sdec[lr];
        if (dp >= 0) {
            float4 ev = *(const float4*)(emb + (size_t)dp * D + chunk * 4);
            *(float4*)(outq + (size_t)(rows0 + lr) * D + chunk * 4) = ev;
        }
    }
}

// batched np-f32-exact resolve: RB rows per block-pass share one eT stream
__global__ __launch_bounds__(256) void vq_resolve(
    const float* __restrict__ x, const float* __restrict__ emb,
    const float* __restrict__ eT, const float* __restrict__ eenp,
    int N, int K,
    float* __restrict__ outq, float* __restrict__ outidx,
    double* __restrict__ lossR,
    const unsigned* __restrict__ nunc, const unsigned* __restrict__ list) {
    const unsigned n = *nunc;
    const int tid = threadIdx.x;
    const int w = tid >> 6, l = tid & 63;
    const f32x4* eT4 = (const f32x4*)eT;  // [D][K/4]
    __shared__ float sxr[RB][64];
    __shared__ float sxx[RB];
    __shared__ float swm[RB][4];
    __shared__ int swi[RB][4];
    __shared__ int sres[RB];
    double lacc = 0.0;

    for (unsigned base = blockIdx.x * RB; base < n; base += gridDim.x * RB) {
        const int nb = (int)(n - base < (unsigned)RB ? n - base : (unsigned)RB);
        // load nb x rows into LDS (coalesced-ish, 2 passes)
#pragma unroll
        for (int i = tid; i < RB * 64; i += 256) {
            int r = i >> 6, d = i & 63;
            if (r < nb) sxr[r][d] = x[(size_t)list[base + r] * D + d];
        }
        __syncthreads();
        if (tid < nb) sxx[tid] = np_pairwise_sumsq64(&sxr[tid][0]);
        __syncthreads();

        // joint d-loop: ONE eT stream for all RB rows
        f32x4 dt[RB];
#pragma unroll
        for (int r = 0; r < RB; ++r) dt[r] = (f32x4){0.f, 0.f, 0.f, 0.f};
#pragma unroll 4
        for (int d = 0; d < D; ++d) {
            f32x4 ev = eT4[(size_t)d * 256 + tid];
#pragma unroll
            for (int r = 0; r < RB; ++r) {
                float xv = sxr[r][d];
                dt[r][0] = __fmaf_rn(xv, ev[0], dt[r][0]);
                dt[r][1] = __fmaf_rn(xv, ev[1], dt[r][1]);
                dt[r][2] = __fmaf_rn(xv, ev[2], dt[r][2]);
                dt[r][3] = __fmaf_rn(xv, ev[3], dt[r][3]);
            }
        }

        // per row: np-exact argmin over this thread's 4 codes, then merges
#pragma unroll
        for (int r = 0; r < RB; ++r) {
            if (r >= nb) break;
            float xx = sxx[r];
            float bm = 1e30f;
            int bi = 0;
#pragma unroll
            for (int jj = 0; jj < 4; ++jj) {
                int k = (tid << 2) + jj;  // ascending within thread
                float dist = __fsub_rn(__fadd_rn(xx, eenp[k]),
                                       __fmul_rn(2.0f, dt[r][jj]));
                if (dist < bm) { bm = dist; bi = k; }
            }
#pragma unroll
            for (int off = 1; off < 64; off <<= 1) {
                float ov = __shfl_xor(bm, off);
                int oi = __shfl_xor(bi, off);
                if (ov < bm || (ov == bm && oi < bi)) { bm = ov; bi = oi; }
            }
            if (l == 0) { swm[r][w] = bm; swi[r][w] = bi; }
        }
        __syncthreads();
        if (tid < nb) {  // thread r finalizes row r (ascending wave order)
            float fm = swm[tid][0];
            int fi = swi[tid][0];
#pragma unroll
            for (int ww = 1; ww < 4; ++ww) {
                float ov = swm[tid][ww];
                int oi = swi[tid][ww];
                if (ov < fm || (ov == fm && oi < fi)) { fm = ov; fi = oi; }
            }
            sres[tid] = fi;
            outidx[list[base + tid]] = (float)fi;
            lacc += (double)fm;  // per-thread partial (threads 0..nb-1)
        }
        __syncthreads();
        // quantized write for resolved rows
        for (int i = tid; i < RB * 64; i += 256) {
            int r = i >> 6, d = i & 63;
            if (r < nb)
                outq[(size_t)list[base + r] * D + d] =
                    emb[(size_t)sres[r] * D + d];
        }
        __syncthreads();
    }
    // reduce lacc (only threads 0..RB-1 ever nonzero) -> plain store
#pragma unroll
    for (int off = 32; off; off >>= 1) lacc += __shfl_down(lacc, off);
    __shared__ double lsw;
    if (tid == 0) lsw = lacc;
    __syncthreads();
    if (tid == 0) lossR[blockIdx.x] = lsw;
}

// histogram of outidx via LDS (16 fat blocks) + last-block finalize
__global__ __launch_bounds__(256) void vq_histperp(
    const float* __restrict__ outidx, int N, int K,
    unsigned* __restrict__ counts, unsigned* __restrict__ done,
    const double* __restrict__ lossA, int nA,
    const double* __restrict__ lossR, int nR,
    float* __restrict__ out_loss, float* __restrict__ out_perp) {
    __shared__ unsigned h[1024];
    __shared__ unsigned rank_s;
#pragma unroll
    for (int i = 0; i < 4; ++i) h[threadIdx.x + 256 * i] = 0;
    __syncthreads();
    int per = N / gridDim.x;
    int base = blockIdx.x * per;
    for (int i = threadIdx.x; i < per; i += 256) {
        int k = (int)outidx[base + i];
        atomicAdd(&h[k], 1u);
    }
    __syncthreads();
#pragma unroll
    for (int i = 0; i < 4; ++i) {
        int b = threadIdx.x + 256 * i;
        unsigned v = h[b];
        if (b < K && v) atomicAdd(counts + b, v);
    }
    __threadfence();
    if (threadIdx.x == 0) rank_s = atomicAdd(done, 1u);
    __syncthreads();
    if (rank_s == gridDim.x - 1) {  // last block: counts complete
        double part = 0.0;
        for (int k = threadIdx.x; k < K; k += 256) {
            // device-scope atomic read (cross-XCD-safe)
            unsigned c = atomicAdd(counts + k, 0u);
            double p = (double)c / (double)N;
            part += p * log(p + 1e-10);
        }
        double lsum = 0.0;
        for (int i = threadIdx.x; i < nA; i += 256) lsum += lossA[i];
        for (int i = threadIdx.x; i < nR; i += 256) lsum += lossR[i];
#pragma unroll
        for (int off = 32; off; off >>= 1) {
            part += __shfl_down(part, off);
            lsum += __shfl_down(lsum, off);
        }
        __shared__ double ls[4], ls2[4];
        if ((threadIdx.x & 63) == 0) {
            ls[threadIdx.x >> 6] = part;
            ls2[threadIdx.x >> 6] = lsum;
        }
        __syncthreads();
        if (threadIdx.x == 0) {
            double s = ls[0] + ls[1] + ls[2] + ls[3];
            double L = ls2[0] + ls2[1] + ls2[2] + ls2[3];
            *out_perp = (float)exp(-s);
            *out_loss = (float)(1.25 * (L / ((double)N * (double)D)));
        }
    }
}

extern "C" void kernel_launch(void* const* d_in, const int* in_sizes, int n_in,
                              void* d_out, int out_size, void* d_ws, size_t ws_size,
                              hipStream_t stream) {
    const float* x = (const float*)d_in[0];
    const float* emb = (const float*)d_in[1];
    int N = in_sizes[0] / D;
    int K = in_sizes[1] / D;

    float* outq = (float*)d_out;
    float* out_loss = outq + (size_t)N * D;
    float* outidx = out_loss + 1;
    float* out_perp = outidx + N;

    char* ws = (char*)d_ws;
    unsigned* counts = (unsigned*)ws;                          // K*4
    unsigned* done = (unsigned*)(ws + (size_t)K * 4);          // 4
    unsigned* nunc = (unsigned*)(ws + (size_t)K * 4 + 4);      // 4 (+8 pad)
    size_t off = (size_t)K * 4 + 16;
    float* neh = (float*)(ws + off);            off += (size_t)K * 4;
    float* eenp = (float*)(ws + off);           off += (size_t)K * 4;
    unsigned short* ehs = (unsigned short*)(ws + off);  off += (size_t)K * 256;
    float* eT = (float*)(ws + off);              off += (size_t)K * D * 4;
    float* m1p = (float*)(ws + off);             off += (size_t)KS * N * 4;
    float* m2p = (float*)(ws + off);             off += (size_t)KS * N * 4;
    int* bip = (int*)(ws + off);                 off += (size_t)KS * N * 4;
    float* xxp = (float*)(ws + off);             off += (size_t)N * 4;
    unsigned* list = (unsigned*)(ws + off);      off += (size_t)N * 4;
    int nA = N / 64, nR = 128;
    double* lossA = (double*)(ws + off);         off += (size_t)nA * 8;
    double* lossR = (double*)(ws + off);         off += (size_t)nR * 8;

    // prep: 64 ehs + 4 sums + 256 eT + 1 zero-counters = 325 blocks
    vq_prep_all<<<325, 256, 0, stream>>>(emb, K, eenp, neh, ehs, eT,
                                         counts, done, nunc);
    vq_screen<<<(N / 256) * KS, 256, 0, stream>>>(x, ehs, neh, N, K,
                                                  m1p, m2p, bip, xxp);
    vq_epilogue<<<N / 64, 256, 0, stream>>>(emb, m1p, m2p, bip, xxp, N,
                                            outq, outidx, lossA, nunc, list);
    vq_resolve<<<128, 256, 0, stream>>>(x, emb, eT, eenp, N, K,
                                        outq, outidx, lossR, nunc, list);
    vq_histperp<<<16, 256, 0, stream>>>(outidx, N, K, counts, done,
                                        lossA, nA, lossR, nR,
                                        out_loss, out_perp);
}

// Round 21
// 164.957 us; speedup vs baseline: 1.1787x; 1.0085x over previous
//
#include <hip/hip_runtime.h>
#include <hip/hip_bf16.h>

#define D 64
#define MARGIN 8e-5f   // covers np-noise (1.6e-5) + 9-bit packing (~2e-6)
#define RB 8           // resolve batch: rows per block-pass (shares eT stream)

typedef __attribute__((ext_vector_type(8))) short bf16x8;
typedef __attribute__((ext_vector_type(4))) float f32x4;
typedef __attribute__((ext_vector_type(4))) unsigned uint4v;

// ---------------------------------------------------------------------------
// VectorQuantizer — 4-node pipeline: prep -> main(scan+decide) -> resolve ->
// histperp. Harness ref = numpy-f32 recompute; argmin must bit-match np-f32
// (xx pairwise-8 sum, sequential-d FMA sgemm, first-min). vq_main: 512-thr
// block = 8 waves (4 row-quads x 2 k-halves); each half runs the proven scan
// (split-bf16 MFMA proxy acc = dot - ee/2, 6-MFMA chain seeded C = -ee/2,
// argmax(acc)==argmin(dist); tile-major codes LDS-staged double-buffered ->
// 1 VMEM/wave/tile; packed top-2: low 9 mantissa bits = complemented local
// idx, med3+max update). Halves merge in-LDS (packed compare; high-bit ties
// land in MARGIN band -> exact resolve), decide, ballot+rank ambiguous list
// (1 u32 atomic/wave), plain lossA store (R13: NO f64 atomics), coalesced
// quantized write (skip ambiguous). NO SoA planes (R20 tail lesson: plane
// round-trip + extra node ~ 20us). vq_resolve: batched np-f32-exact, 8 rows
// share one eT stream (R19 lesson). vq_histperp: 16-block LDS hist (R17
// lesson: direct counts atomics serialize) + last-block finalize.
// d_out (float): quantized[N*D] | loss[1] | indices[N] | perplexity[1]
// ws: counts u32[K] | done u32 | nunc u32 | pad | neh f32[K] | eenp f32[K]
//     | ehs bf16-tiles[K*256B] | eT f32[D*K] | list u32[N]
//     | lossA f64[N/256] | lossR f64[128]
// ---------------------------------------------------------------------------

__device__ __forceinline__ float np_pairwise_sumsq64(const float* a) {
    float r[8];
#pragma unroll
    for (int j = 0; j < 8; ++j) r[j] = __fmul_rn(a[j], a[j]);
#pragma unroll
    for (int i = 8; i < 64; i += 8)
#pragma unroll
        for (int j = 0; j < 8; ++j)
            r[j] = __fadd_rn(r[j], __fmul_rn(a[i + j], a[i + j]));
    return __fadd_rn(
        __fadd_rn(__fadd_rn(r[0], r[1]), __fadd_rn(r[2], r[3])),
        __fadd_rn(__fadd_rn(r[4], r[5]), __fadd_rn(r[6], r[7])));
}

#define CVT8(F0, F1, H, L)                                                    \
    do {                                                                      \
        float _f[8] = {F0.x, F0.y, F0.z, F0.w, F1.x, F1.y, F1.z, F1.w};       \
        _Pragma("unroll") for (int _i = 0; _i < 8; ++_i) {                    \
            unsigned _u = __float_as_uint(_f[_i]);                            \
            unsigned _hb = (_u + 0x7fffu + ((_u >> 16) & 1u)) >> 16;          \
            float _hf = __uint_as_float(_hb << 16);                           \
            float _r = _f[_i] - _hf;                                          \
            unsigned _u2 = __float_as_uint(_r);                               \
            unsigned _lb = (_u2 + 0x7fffu + ((_u2 >> 16) & 1u)) >> 16;        \
            H[_i] = (short)_hb;                                               \
            L[_i] = (short)_lb;                                               \
        }                                                                     \
    } while (0)

// prep: [0,64) ehs tile-major; [64,68) sumsq; [68,324) eT; 324 zero counters
__global__ __launch_bounds__(256) void vq_prep_all(
    const float* __restrict__ emb, int K,
    float* __restrict__ eenp, float* __restrict__ neh,
    unsigned short* __restrict__ ehs, float* __restrict__ eT,
    unsigned* __restrict__ counts, unsigned* __restrict__ done,
    unsigned* __restrict__ nunc) {
    int b = blockIdx.x;
    if (b < 64) {
        int t = b * 256 + threadIdx.x;     // (tile, sec, lane): 16384 frags
        int tile = t >> 8, r = t & 255, s = r >> 6, l = r & 63;
        int sub = l & 15, grp = l >> 4;
        int k = tile * 16 + sub;
        int d0 = ((s & 1) << 5) + (grp << 3);
        const float* e = emb + (size_t)k * D + d0;
        float4 f0 = *(const float4*)e;
        float4 f1 = *(const float4*)(e + 4);
        bf16x8 h, lo;
        CVT8(f0, f1, h, lo);
        *(bf16x8*)(ehs + (size_t)t * 8) = (s >> 1) ? lo : h;  // s0,s1=eh s2,s3=el
    } else if (b < 68) {
        int k = (b - 64) * 256 + threadIdx.x;   // 1024 codes
        float s = np_pairwise_sumsq64(emb + (size_t)k * D);
        eenp[k] = s;
        neh[k] = -0.5f * s;
    } else if (b < 324) {
        int t = (b - 68) * 256 + threadIdx.x;   // 65536 = D*K, coalesced write
        int d = t / K, k = t - d * K;
        eT[t] = emb[(size_t)k * D + d];
    } else {
#pragma unroll
        for (int i = 0; i < 4; ++i) {
            int c = threadIdx.x + 256 * i;
            if (c < K) counts[c] = 0u;
        }
        if (threadIdx.x == 0) { *done = 0u; *nunc = 0u; }
    }
}

// fused scan + decide + quantized write. 512 threads: 8 waves = 4 row-quads
// x 2 k-halves. 256 rows per block.
__global__ __launch_bounds__(512) void vq_main(
    const float* __restrict__ x, const unsigned short* __restrict__ ehs,
    const float* __restrict__ neh, const float* __restrict__ emb,
    int N, int K,
    float* __restrict__ outq, float* __restrict__ outidx,
    double* __restrict__ lossA,
    unsigned* __restrict__ nunc, unsigned* __restrict__ list) {
    const int tid = threadIdx.x;
    const int lane = tid & 63;
    const int wid = tid >> 6;
    const int half = wid >> 2;           // k-slice 0/1
    const int wq = wid & 3;              // row quad
    const int rows0 = blockIdx.x * 256;
    const int row0 = rows0 + wq * 64;    // 64 rows/wave
    const int sub = lane & 15, grp = lane >> 4;
    const int g4 = grp << 2;
    const int k0 = half * (K >> 1);
    const int NT = (K >> 1) >> 4;        // 32 tiles per half
    const int t0 = k0 >> 4;

    __shared__ __align__(16) unsigned short lds[2][2][2048];  // [half][buf]
    __shared__ float sm1[2][256], sm2[2][256], sxx[256];
    __shared__ int sdec[256];
    __shared__ double ls[4];

    // persistent B frags: x rows, split bf16, 4 row-tiles x 2 k-slices.
    // Also per-lane sumsq (loss-only, f32), grp-reduced -> row xx.
    bf16x8 xh[4][2], xl[4][2];
    float xq[4];
#pragma unroll
    for (int rt = 0; rt < 4; ++rt) {
        xq[rt] = 0.f;
        const float* xrow = x + (((size_t)(row0 + (rt << 4) + sub)) << 6) + (grp << 3);
#pragma unroll
        for (int s = 0; s < 2; ++s) {
            float4 f0 = *(const float4*)(xrow + (s << 5));
            float4 f1 = *(const float4*)(xrow + (s << 5) + 4);
            xq[rt] = fmaf(f0.x, f0.x, xq[rt]); xq[rt] = fmaf(f0.y, f0.y, xq[rt]);
            xq[rt] = fmaf(f0.z, f0.z, xq[rt]); xq[rt] = fmaf(f0.w, f0.w, xq[rt]);
            xq[rt] = fmaf(f1.x, f1.x, xq[rt]); xq[rt] = fmaf(f1.y, f1.y, xq[rt]);
            xq[rt] = fmaf(f1.z, f1.z, xq[rt]); xq[rt] = fmaf(f1.w, f1.w, xq[rt]);
            CVT8(f0, f1, xh[rt][s], xl[rt][s]);
        }
    }
#pragma unroll
    for (int rt = 0; rt < 4; ++rt) {
        xq[rt] += __shfl_xor(xq[rt], 16);
        xq[rt] += __shfl_xor(xq[rt], 32);  // lane<16 holds full row xx
    }

    // packed top-2: low 9 mantissa bits = complemented half-local code idx
    float m1[4], m2[4];
#pragma unroll
    for (int rt = 0; rt < 4; ++rt) { m1[rt] = -3e38f; m2[rt] = -3e38f; }

    // staging: wave wq stages section wq of its half's tile
    const unsigned short* sbase = ehs + ((size_t)t0 << 11);  // 2048 ush/tile
    const int slot = (wq << 9) + (lane << 3);                // ushort offset

    uint4v tmp = *(const uint4v*)(sbase + slot);             // tile 0
    *(uint4v*)&lds[half][0][slot] = tmp;
    __syncthreads();

    for (int t = 0; t < NT; ++t) {
        const int cur = t & 1;
        if (t + 1 < NT)  // T14: issue next-tile load before compute
            tmp = *(const uint4v*)(sbase + ((size_t)(t + 1) << 11) + slot);

        f32x4 cb = *(const f32x4*)(neh + k0 + (t << 4) + g4);
        const bf16x8* L = (const bf16x8*)&lds[half][cur][0];
        bf16x8 a0 = L[lane];        // eh d[0,32)
        bf16x8 a1 = L[64 + lane];   // eh d[32,64)
        bf16x8 a2 = L[128 + lane];  // el d[0,32)
        bf16x8 a3 = L[192 + lane];  // el d[32,64)

        f32x4 acc[4];
#pragma unroll
        for (int rt = 0; rt < 4; ++rt)
            acc[rt] = __builtin_amdgcn_mfma_f32_16x16x32_bf16(a0, xh[rt][0], cb, 0, 0, 0);
#pragma unroll
        for (int rt = 0; rt < 4; ++rt)
            acc[rt] = __builtin_amdgcn_mfma_f32_16x16x32_bf16(a2, xh[rt][0], acc[rt], 0, 0, 0);
#pragma unroll
        for (int rt = 0; rt < 4; ++rt)
            acc[rt] = __builtin_amdgcn_mfma_f32_16x16x32_bf16(a0, xl[rt][0], acc[rt], 0, 0, 0);
#pragma unroll
        for (int rt = 0; rt < 4; ++rt)
            acc[rt] = __builtin_amdgcn_mfma_f32_16x16x32_bf16(a1, xh[rt][1], acc[rt], 0, 0, 0);
#pragma unroll
        for (int rt = 0; rt < 4; ++rt)
            acc[rt] = __builtin_amdgcn_mfma_f32_16x16x32_bf16(a3, xh[rt][1], acc[rt], 0, 0, 0);
#pragma unroll
        for (int rt = 0; rt < 4; ++rt)
            acc[rt] = __builtin_amdgcn_mfma_f32_16x16x32_bf16(a1, xl[rt][1], acc[rt], 0, 0, 0);

        // packed top-2 update: 3 VALU/value (and_or + med3 + max)
        const int baset = 511 - (t << 4) - g4;
#pragma unroll
        for (int rt = 0; rt < 4; ++rt) {
#pragma unroll
            for (int j = 0; j < 4; ++j) {
                unsigned pv = (__float_as_uint(acc[rt][j]) & 0xFFFFFE00u)
                              | (unsigned)(baset - j);
                float p = __uint_as_float(pv);
                m2[rt] = fminf(fmaxf(p, m2[rt]), m1[rt]);  // med3(p,m2,m1)
                m1[rt] = fmaxf(p, m1[rt]);
            }
        }

        if (t + 1 < NT)  // T14: write-late into the other buffer
            *(uint4v*)&lds[half][cur ^ 1][slot] = tmp;
        __syncthreads();
    }

    // merge the 4 code-groups: pure min/max on packed values
#pragma unroll
    for (int rt = 0; rt < 4; ++rt) {
#pragma unroll
        for (int off = 16; off <= 32; off <<= 1) {
            float om1 = __shfl_xor(m1[rt], off);
            float om2 = __shfl_xor(m2[rt], off);
            float lo = fminf(m1[rt], om1);
            m1[rt] = fmaxf(m1[rt], om1);
            m2[rt] = fmaxf(lo, fmaxf(m2[rt], om2));
        }
    }

    // per-half results -> LDS (lanes 0-15 own 16 consecutive rows per rt)
    if (lane < 16) {
#pragma unroll
        for (int rt = 0; rt < 4; ++rt) {
            int lr = wq * 64 + (rt << 4) + lane;
            sm1[half][lr] = m1[rt];
            sm2[half][lr] = m2[rt];
            if (half == 0) sxx[lr] = xq[rt];
        }
    }
    __syncthreads();

    // decide: waves 0-3, thread lr<256 merges the two halves for local row lr
    if (tid < 256) {
        const int lr = tid;
        const int r = rows0 + lr;
        float m1a = sm1[0][lr], m1b = sm1[1][lr];
        float m2a = sm2[0][lr], m2b = sm2[1][lr];
        bool take = m1b > m1a;  // strict: equal high-bit ties -> MARGIN band
        float gm1 = fmaxf(m1a, m1b);
        float gm2 = fmaxf(fminf(m1a, m1b), fmaxf(m2a, m2b));
        int loc = 511 - (int)(__float_as_uint(gm1) & 511u);
        int k = (take ? (K >> 1) : 0) + loc;
        bool amb = 2.0f * (gm1 - gm2) < MARGIN;
        unsigned long long mask = __ballot(amb);
        int cnt = __popcll(mask);
        unsigned base = 0;
        if (lane == 0 && cnt) base = atomicAdd(nunc, (unsigned)cnt);
        base = __shfl(base, 0);
        int dec = k;
        double lpart = 0.0;
        if (amb) {
            int rank = __popcll(mask & ((1ull << lane) - 1ull));
            list[base + rank] = (unsigned)r;
            dec = -1;
        } else {
            outidx[r] = (float)dec;
            // strip 9 packed index bits, then ||x-e||^2 = xx - 2*m1
            float gm1v = __uint_as_float(__float_as_uint(gm1) & 0xFFFFFE00u);
            lpart = (double)(sxx[lr] - 2.0f * gm1v);
        }
        sdec[lr] = dec;
#pragma unroll
        for (int off = 32; off; off >>= 1) lpart += __shfl_down(lpart, off);
        if (lane == 0) ls[wid] = lpart;
    }
    __syncthreads();
    if (tid == 0)
        lossA[blockIdx.x] = ls[0] + ls[1] + ls[2] + ls[3];  // plain store

    // quantized gather-write: 512 threads, wave-contiguous 1KB per pass
    const int chunk = tid & 15, rl = tid >> 4;  // 32 rows x 16 chunks
#pragma unroll
    for (int p = 0; p < 8; ++p) {
        int lr = p * 32 + rl;
        int dp = sdec[lr];
        if (dp >= 0) {
            float4 ev = *(const float4*)(emb + (size_t)dp * D + chunk * 4);
            *(float4*)(outq + (size_t)(rows0 + lr) * D + chunk * 4) = ev;
        }
    }
}

// batched np-f32-exact resolve: RB rows per block-pass share one eT stream
__global__ __launch_bounds__(256) void vq_resolve(
    const float* __restrict__ x, const float* __restrict__ emb,
    const float* __restrict__ eT, const float* __restrict__ eenp,
    int N, int K,
    float* __restrict__ outq, float* __restrict__ outidx,
    double* __restrict__ lossR,
    const unsigned* __restrict__ nunc, const unsigned* __restrict__ list) {
    const unsigned n = *nunc;
    const int tid = threadIdx.x;
    const int w = tid >> 6, l = tid & 63;
    const f32x4* eT4 = (const f32x4*)eT;  // [D][K/4]
    __shared__ float sxr[RB][64];
    __shared__ float sxx[RB];
    __shared__ float swm[RB][4];
    __shared__ int swi[RB][4];
    __shared__ int sres[RB];
    double lacc = 0.0;

    for (unsigned base = blockIdx.x * RB; base < n; base += gridDim.x * RB) {
        const int nb = (int)(n - base < (unsigned)RB ? n - base : (unsigned)RB);
#pragma unroll
        for (int i = tid; i < RB * 64; i += 256) {
            int r = i >> 6, d = i & 63;
            if (r < nb) sxr[r][d] = x[(size_t)list[base + r] * D + d];
        }
        __syncthreads();
        if (tid < nb) sxx[tid] = np_pairwise_sumsq64(&sxr[tid][0]);
        __syncthreads();

        // joint d-loop: ONE eT stream for all RB rows
        f32x4 dt[RB];
#pragma unroll
        for (int r = 0; r < RB; ++r) dt[r] = (f32x4){0.f, 0.f, 0.f, 0.f};
#pragma unroll 4
        for (int d = 0; d < D; ++d) {
            f32x4 ev = eT4[(size_t)d * 256 + tid];
#pragma unroll
            for (int r = 0; r < RB; ++r) {
                float xv = sxr[r][d];
                dt[r][0] = __fmaf_rn(xv, ev[0], dt[r][0]);
                dt[r][1] = __fmaf_rn(xv, ev[1], dt[r][1]);
                dt[r][2] = __fmaf_rn(xv, ev[2], dt[r][2]);
                dt[r][3] = __fmaf_rn(xv, ev[3], dt[r][3]);
            }
        }

#pragma unroll
        for (int r = 0; r < RB; ++r) {
            if (r >= nb) break;
            float xx = sxx[r];
            float bm = 1e30f;
            int bi = 0;
#pragma unroll
            for (int jj = 0; jj < 4; ++jj) {
                int k = (tid << 2) + jj;  // ascending within thread
                float dist = __fsub_rn(__fadd_rn(xx, eenp[k]),
                                       __fmul_rn(2.0f, dt[r][jj]));
                if (dist < bm) { bm = dist; bi = k; }
            }
#pragma unroll
            for (int off = 1; off < 64; off <<= 1) {
                float ov = __shfl_xor(bm, off);
                int oi = __shfl_xor(bi, off);
                if (ov < bm || (ov == bm && oi < bi)) { bm = ov; bi = oi; }
            }
            if (l == 0) { swm[r][w] = bm; swi[r][w] = bi; }
        }
        __syncthreads();
        if (tid < nb) {  // thread r finalizes row r (ascending wave order)
            float fm = swm[tid][0];
            int fi = swi[tid][0];
#pragma unroll
            for (int ww = 1; ww < 4; ++ww) {
                float ov = swm[tid][ww];
                int oi = swi[tid][ww];
                if (ov < fm || (ov == fm && oi < fi)) { fm = ov; fi = oi; }
            }
            sres[tid] = fi;
            outidx[list[base + tid]] = (float)fi;
            lacc += (double)fm;
        }
        __syncthreads();
        for (int i = tid; i < RB * 64; i += 256) {
            int r = i >> 6, d = i & 63;
            if (r < nb)
                outq[(size_t)list[base + r] * D + d] =
                    emb[(size_t)sres[r] * D + d];
        }
        __syncthreads();
    }
#pragma unroll
    for (int off = 32; off; off >>= 1) lacc += __shfl_down(lacc, off);
    __shared__ double lsw;
    if (tid == 0) lsw = lacc;
    __syncthreads();
    if (tid == 0) lossR[blockIdx.x] = lsw;
}

// histogram of outidx via LDS (16 fat blocks) + last-block finalize
__global__ __launch_bounds__(256) void vq_histperp(
    const float* __restrict__ outidx, int N, int K,
    unsigned* __restrict__ counts, unsigned* __restrict__ done,
    const double* __restrict__ lossA, int nA,
    const double* __restrict__ lossR, int nR,
    float* __restrict__ out_loss, float* __restrict__ out_perp) {
    __shared__ unsigned h[1024];
    __shared__ unsigned rank_s;
#pragma unroll
    for (int i = 0; i < 4; ++i) h[threadIdx.x + 256 * i] = 0;
    __syncthreads();
    int per = N / gridDim.x;
    int base = blockIdx.x * per;
    for (int i = threadIdx.x; i < per; i += 256) {
        int k = (int)outidx[base + i];
        atomicAdd(&h[k], 1u);
    }
    __syncthreads();
#pragma unroll
    for (int i = 0; i < 4; ++i) {
        int b = threadIdx.x + 256 * i;
        unsigned v = h[b];
        if (b < K && v) atomicAdd(counts + b, v);
    }
    __threadfence();
    if (threadIdx.x == 0) rank_s = atomicAdd(done, 1u);
    __syncthreads();
    if (rank_s == gridDim.x - 1) {  // last block: counts complete
        double part = 0.0;
        for (int k = threadIdx.x; k < K; k += 256) {
            unsigned c = atomicAdd(counts + k, 0u);  // device-scope read
            double p = (double)c / (double)N;
            part += p * log(p + 1e-10);
        }
        double lsum = 0.0;
        for (int i = threadIdx.x; i < nA; i += 256) lsum += lossA[i];
        for (int i = threadIdx.x; i < nR; i += 256) lsum += lossR[i];
#pragma unroll
        for (int off = 32; off; off >>= 1) {
            part += __shfl_down(part, off);
            lsum += __shfl_down(lsum, off);
        }
        __shared__ double ls[4], ls2[4];
        if ((threadIdx.x & 63) == 0) {
            ls[threadIdx.x >> 6] = part;
            ls2[threadIdx.x >> 6] = lsum;
        }
        __syncthreads();
        if (threadIdx.x == 0) {
            double s = ls[0] + ls[1] + ls[2] + ls[3];
            double L = ls2[0] + ls2[1] + ls2[2] + ls2[3];
            *out_perp = (float)exp(-s);
            *out_loss = (float)(1.25 * (L / ((double)N * (double)D)));
        }
    }
}

extern "C" void kernel_launch(void* const* d_in, const int* in_sizes, int n_in,
                              void* d_out, int out_size, void* d_ws, size_t ws_size,
                              hipStream_t stream) {
    const float* x = (const float*)d_in[0];
    const float* emb = (const float*)d_in[1];
    int N = in_sizes[0] / D;
    int K = in_sizes[1] / D;

    float* outq = (float*)d_out;
    float* out_loss = outq + (size_t)N * D;
    float* outidx = out_loss + 1;
    float* out_perp = outidx + N;

    char* ws = (char*)d_ws;
    unsigned* counts = (unsigned*)ws;                          // K*4
    unsigned* done = (unsigned*)(ws + (size_t)K * 4);          // 4
    unsigned* nunc = (unsigned*)(ws + (size_t)K * 4 + 4);      // 4 (+8 pad)
    size_t off = (size_t)K * 4 + 16;
    float* neh = (float*)(ws + off);            off += (size_t)K * 4;
    float* eenp = (float*)(ws + off);           off += (size_t)K * 4;
    unsigned short* ehs = (unsigned short*)(ws + off);  off += (size_t)K * 256;
    float* eT = (float*)(ws + off);              off += (size_t)K * D * 4;
    unsigned* list = (unsigned*)(ws + off);      off += (size_t)N * 4;
    int nA = N / 256, nR = 128;
    double* lossA = (double*)(ws + off);         off += (size_t)nA * 8;
    double* lossR = (double*)(ws + off);         off += (size_t)nR * 8;

    // prep: 64 ehs + 4 sums + 256 eT + 1 zero-counters = 325 blocks
    vq_prep_all<<<325, 256, 0, stream>>>(emb, K, eenp, neh, ehs, eT,
                                         counts, done, nunc);
    vq_main<<<N / 256, 512, 0, stream>>>(x, ehs, neh, emb, N, K,
                                         outq, outidx, lossA, nunc, list);
    vq_resolve<<<128, 256, 0, stream>>>(x, emb, eT, eenp, N, K,
                                        outq, outidx, lossR, nunc, list);
    vq_histperp<<<16, 256, 0, stream>>>(outidx, N, K, counts, done,
                                        lossA, nA, lossR, nR,
                                        out_loss, out_perp);
}